// Round 1
// baseline (844.366 us; speedup 1.0000x reference)
//
#include <hip/hip_runtime.h>
#include <math.h>

#define BATCH 16384
#define HDIM  256
#define DIN   228    // 128 latent + 100 cond
#define K2DIM 484    // HDIM + DIN
#define DOUTN 2100
#define NGRP  200    // 100 continuous (11 cols) + 100 discrete (10 cols)

// ---------------------------------------------------------------------------
// i0 = concat(z, c) loader (row-major, k in [0, 228))
// ---------------------------------------------------------------------------
__device__ __forceinline__ double load_i0(const float* __restrict__ z,
                                          const float* __restrict__ c,
                                          int row, int k) {
    return (k < 128) ? (double)z[(size_t)row * 128 + k]
                     : (double)c[(size_t)row * 100 + (k - 128)];
}

// ---------------------------------------------------------------------------
// Generic f64-accumulate tiled GEMM.
// MODE 0: h1 = i0 @ W1 + b1                      (K=228,  N=256, out f64)
// MODE 1: h2 = [bnrelu(h1), i0] @ W2 + b2        (K=484,  N=256, out f64)
// MODE 2: x  = bnrelu(h2) @ Wout + bout          (K=256,  N=2100, out f32)
// BN applied on-the-fly on A-load as h*sc[k]+sh[k], relu'd.
// 64x64 block tile, 16 K-tile, 4x4 microtile per thread (256 threads).
// ---------------------------------------------------------------------------
template <int MODE>
__global__ __launch_bounds__(256) void gemm_k(
    const float*  __restrict__ z,   const float*  __restrict__ c,
    const double* __restrict__ hin,
    const double* __restrict__ sc,  const double* __restrict__ sh,
    const float*  __restrict__ W,   const float*  __restrict__ bias,
    double* __restrict__ hout,      float* __restrict__ xout)
{
    constexpr int K  = (MODE == 0) ? DIN : (MODE == 1) ? K2DIM : HDIM;
    constexpr int N  = (MODE == 2) ? DOUTN : HDIM;
    constexpr int KT = 16, BM = 64, BN = 64;

    __shared__ double Ash[KT][BM + 2];   // transposed: Ash[k][row], stride 66*8B (16B aligned)
    __shared__ double Bsh[KT][BN + 2];

    const int tid  = threadIdx.x;
    const int row0 = blockIdx.y * BM;
    const int n0   = blockIdx.x * BN;
    const int ty   = tid >> 4;          // 0..15
    const int tx   = tid & 15;          // 0..15

    double acc[4][4] = {};

    for (int kt = 0; kt < K; kt += KT) {
        __syncthreads();
        // ---- stage A tile (with BN+relu where applicable) ----
        #pragma unroll
        for (int e = tid; e < BM * KT; e += 256) {
            const int rl = e >> 4;          // row within tile
            const int kk = e & 15;
            const int gk = kt + kk;
            double v = 0.0;
            if (MODE == 0) {
                if (gk < DIN) v = load_i0(z, c, row0 + rl, gk);
            } else if (MODE == 1) {
                if (gk < HDIM) {
                    const double h = hin[(size_t)(row0 + rl) * HDIM + gk];
                    const double s = fma(h, sc[gk], sh[gk]);
                    v = s > 0.0 ? s : 0.0;
                } else if (gk < K2DIM) {
                    v = load_i0(z, c, row0 + rl, gk - HDIM);
                }
            } else {
                const double h = hin[(size_t)(row0 + rl) * HDIM + gk];
                const double s = fma(h, sc[gk], sh[gk]);
                v = s > 0.0 ? s : 0.0;
            }
            Ash[kk][rl] = v;
        }
        // ---- stage B tile ----
        #pragma unroll
        for (int e = tid; e < KT * BN; e += 256) {
            const int kk = e >> 6;          // 0..15
            const int nn = e & 63;
            const int gk = kt + kk, gn = n0 + nn;
            Bsh[kk][nn] = (gk < K && gn < N) ? (double)W[(size_t)gk * N + gn] : 0.0;
        }
        __syncthreads();
        // ---- 4x4 microtile FMA ----
        #pragma unroll
        for (int kk = 0; kk < KT; ++kk) {
            double a[4], b[4];
            #pragma unroll
            for (int i = 0; i < 4; ++i) a[i] = Ash[kk][ty * 4 + i];
            #pragma unroll
            for (int j = 0; j < 4; ++j) b[j] = Bsh[kk][tx * 4 + j];
            #pragma unroll
            for (int i = 0; i < 4; ++i)
                #pragma unroll
                for (int j = 0; j < 4; ++j)
                    acc[i][j] = fma(a[i], b[j], acc[i][j]);
        }
    }

    // ---- epilogue ----
    #pragma unroll
    for (int i = 0; i < 4; ++i) {
        const int row = row0 + ty * 4 + i;
        #pragma unroll
        for (int j = 0; j < 4; ++j) {
            const int n = n0 + tx * 4 + j;
            if (MODE == 2) {
                if (n < N) xout[(size_t)row * N + n] = (float)(acc[i][j] + (double)bias[n]);
            } else {
                hout[(size_t)row * N + n] = acc[i][j] + (double)bias[n];
            }
        }
    }
}

// ---------------------------------------------------------------------------
// Column reductions for BatchNorm stats (deterministic two-stage).
// Stage 1: 256 blocks x 64 rows each -> part[blk][col]
// ---------------------------------------------------------------------------
__global__ __launch_bounds__(256) void colsum_k(const double* __restrict__ h,
                                                double* __restrict__ part,
                                                const double* __restrict__ mu,
                                                int sq)
{
    const int col = threadIdx.x;
    const size_t b0 = (size_t)blockIdx.x * 64;
    double s = 0.0;
    if (!sq) {
        for (int r = 0; r < 64; ++r) s += h[(b0 + r) * HDIM + col];
    } else {
        const double m = mu[col];
        for (int r = 0; r < 64; ++r) {
            const double d = h[(b0 + r) * HDIM + col] - m;
            s = fma(d, d, s);
        }
    }
    part[(size_t)blockIdx.x * HDIM + col] = s;
}

__global__ __launch_bounds__(256) void fin_mu_k(const double* __restrict__ part,
                                                double* __restrict__ mu)
{
    const int col = threadIdx.x;
    double s = 0.0;
    for (int i = 0; i < 256; ++i) s += part[(size_t)i * HDIM + col];
    mu[col] = s / (double)BATCH;
}

__global__ __launch_bounds__(256) void fin_var_k(const double* __restrict__ part,
                                                 const double* __restrict__ mu,
                                                 const float* __restrict__ g,
                                                 const float* __restrict__ be,
                                                 double* __restrict__ sc,
                                                 double* __restrict__ sh)
{
    const int col = threadIdx.x;
    double s = 0.0;
    for (int i = 0; i < 256; ++i) s += part[(size_t)i * HDIM + col];
    const double var   = s / (double)BATCH;
    const double rs    = 1.0 / sqrt(var + 1e-5);
    const double scale = rs * (double)g[col];
    sc[col] = scale;
    sh[col] = (double)be[col] - mu[col] * scale;
}

// ---------------------------------------------------------------------------
// Heads: in-place over x (stored in d_out as f32).
// One thread per (row, group); groups are disjoint -> race-free, deterministic.
// Continuous g<100: col g*11 -> tanh; cols g*11+1..10 -> one-hot argmax(x+gum).
// Discrete  g>=100: cols 1100+(g-100)*10 -> one-hot argmax(x+gum).
// argmax is first-max-wins (strict >), matching np/jnp.argmax.
// ---------------------------------------------------------------------------
__global__ __launch_bounds__(256) void heads_k(float* __restrict__ x,
                                               const float* __restrict__ gc,
                                               const float* __restrict__ gd)
{
    const int idx = blockIdx.x * 256 + threadIdx.x;
    const int row = idx / NGRP;
    const int g   = idx % NGRP;

    if (g < 100) {
        const size_t base = (size_t)row * DOUTN + (size_t)g * 11;
        const float x0 = x[base];
        int am = 0; double best = -1e300;
        #pragma unroll
        for (int m = 0; m < 10; ++m) {
            const double v = (double)x[base + 1 + m] +
                             (double)gc[((size_t)row * 100 + g) * 10 + m];
            if (v > best) { best = v; am = m; }
        }
        x[base] = (float)tanh((double)x0);
        #pragma unroll
        for (int m = 0; m < 10; ++m) x[base + 1 + m] = (m == am) ? 1.0f : 0.0f;
    } else {
        const int gi = g - 100;
        const size_t base = (size_t)row * DOUTN + 1100 + (size_t)gi * 10;
        int am = 0; double best = -1e300;
        #pragma unroll
        for (int m = 0; m < 10; ++m) {
            const double v = (double)x[base + m] +
                             (double)gd[((size_t)row * 100 + gi) * 10 + m];
            if (v > best) { best = v; am = m; }
        }
        #pragma unroll
        for (int m = 0; m < 10; ++m) x[base + m] = (m == am) ? 1.0f : 0.0f;
    }
}

// ---------------------------------------------------------------------------
extern "C" void kernel_launch(void* const* d_in, const int* in_sizes, int n_in,
                              void* d_out, int out_size, void* d_ws, size_t ws_size,
                              hipStream_t stream)
{
    (void)in_sizes; (void)n_in; (void)out_size; (void)ws_size;

    const float* z    = (const float*)d_in[0];
    const float* c    = (const float*)d_in[1];
    const float* W1   = (const float*)d_in[2];
    const float* b1   = (const float*)d_in[3];
    const float* g1   = (const float*)d_in[4];
    const float* be1  = (const float*)d_in[5];
    const float* W2   = (const float*)d_in[6];
    const float* b2   = (const float*)d_in[7];
    const float* g2   = (const float*)d_in[8];
    const float* be2  = (const float*)d_in[9];
    const float* Wout = (const float*)d_in[10];
    const float* bout = (const float*)d_in[11];
    const float* gc   = (const float*)d_in[12];
    const float* gd   = (const float*)d_in[13];
    float* out = (float*)d_out;

    // workspace layout (doubles): h1, h2, part[256][256], mu1, sc1, sh1, mu2, sc2, sh2
    double* h1   = (double*)d_ws;
    double* h2   = h1 + (size_t)BATCH * HDIM;
    double* part = h2 + (size_t)BATCH * HDIM;
    double* mu1  = part + (size_t)256 * HDIM;
    double* sc1  = mu1 + HDIM;
    double* sh1  = sc1 + HDIM;
    double* mu2  = sh1 + HDIM;
    double* sc2  = mu2 + HDIM;
    double* sh2  = sc2 + HDIM;

    const dim3 blk(256);
    const dim3 gridH(HDIM / 64, BATCH / 64);          // (4, 256)
    const dim3 gridO((DOUTN + 63) / 64, BATCH / 64);  // (33, 256)

    // layer 1
    gemm_k<0><<<gridH, blk, 0, stream>>>(z, c, nullptr, nullptr, nullptr, W1, b1, h1, nullptr);
    colsum_k<<<dim3(256), blk, 0, stream>>>(h1, part, nullptr, 0);
    fin_mu_k<<<dim3(1), blk, 0, stream>>>(part, mu1);
    colsum_k<<<dim3(256), blk, 0, stream>>>(h1, part, mu1, 1);
    fin_var_k<<<dim3(1), blk, 0, stream>>>(part, mu1, g1, be1, sc1, sh1);
    // layer 2
    gemm_k<1><<<gridH, blk, 0, stream>>>(z, c, h1, sc1, sh1, W2, b2, h2, nullptr);
    colsum_k<<<dim3(256), blk, 0, stream>>>(h2, part, nullptr, 0);
    fin_mu_k<<<dim3(1), blk, 0, stream>>>(part, mu2);
    colsum_k<<<dim3(256), blk, 0, stream>>>(h2, part, mu2, 1);
    fin_var_k<<<dim3(1), blk, 0, stream>>>(part, mu2, g2, be2, sc2, sh2);
    // output layer (x -> d_out as f32), then heads in-place
    gemm_k<2><<<gridO, blk, 0, stream>>>(z, c, h2, sc2, sh2, Wout, bout, nullptr, out);
    heads_k<<<dim3(BATCH * NGRP / 256), blk, 0, stream>>>(out, gc, gd);
}

// Round 2
// 689.768 us; speedup vs baseline: 1.2241x; 1.2241x over previous
//
#include <hip/hip_runtime.h>
#include <math.h>

#define BATCH 16384
#define HDIM  256
#define DIN   228    // 128 latent + 100 cond
#define K2DIM 484    // HDIM + DIN
#define DOUTN 2100
#define NGRP  200    // 100 continuous (11 cols) + 100 discrete (10 cols)
#define THETA 2e-4   // top-2 gap below this -> f64 recompute (expect ~650 flags)
#define FCAP  16384

// ---------------------------------------------------------------------------
// f32 tiled GEMM, 128x128 block tile, KT=16, 256 threads, 8x8 microtile
// (split 2x2 of 4x4 float4 fragments).
// MODE 0: h1 = i0 @ W1 + b1                      (K=228,  N=256)
// MODE 1: h2 = [bnrelu(h1), i0] @ W2 + b2        (K=484,  N=256)
// MODE 2: x  = bnrelu(h2) @ Wout + bout          (K=256,  N=2100)
// BN+relu applied on A-load via f32 scale/shift.
// ---------------------------------------------------------------------------
template <int MODE>
__global__ __launch_bounds__(256) void gemm_f32(
    const float* __restrict__ z,   const float* __restrict__ c,
    const float* __restrict__ hin,
    const float* __restrict__ scf, const float* __restrict__ shf,
    const float* __restrict__ W,   const float* __restrict__ bias,
    float* __restrict__ out)
{
    constexpr int K  = (MODE == 0) ? DIN : (MODE == 1) ? K2DIM : HDIM;
    constexpr int N  = (MODE == 2) ? DOUTN : HDIM;
    constexpr int KT = 16, BM = 128, BN = 128;

    __shared__ float Ash[KT][BM + 4];   // transposed: Ash[k][row]
    __shared__ float Bsh[KT][BN + 4];

    const int tid  = threadIdx.x;
    const int row0 = blockIdx.y * BM;
    const int n0   = blockIdx.x * BN;
    const int tx   = tid & 15, ty = tid >> 4;
    const int arow = tid >> 1, ahalf = (tid & 1) * 8;   // A stage: row, k-half
    const int bkk  = tid >> 4, bc = (tid & 15) * 8;     // B stage: k, col base
    const bool nfast = (n0 + BN <= N);

    float acc[2][2][4][4] = {};

    for (int kt = 0; kt < K; kt += KT) {
        __syncthreads();
        // ---- A stage (8 elems/thread, mode-specific source + BN) ----
        #pragma unroll
        for (int q = 0; q < 8; ++q) {
            const int gk = kt + ahalf + q;
            float v = 0.f;
            if (MODE == 0) {
                if (gk < DIN)
                    v = (gk < 128) ? z[(size_t)(row0 + arow) * 128 + gk]
                                   : c[(size_t)(row0 + arow) * 100 + gk - 128];
            } else if (MODE == 1) {
                if (gk < HDIM) {
                    const float h = hin[(size_t)(row0 + arow) * HDIM + gk];
                    const float s = fmaf(h, scf[gk], shf[gk]);
                    v = s > 0.f ? s : 0.f;
                } else if (gk < K2DIM) {
                    const int k2 = gk - HDIM;
                    v = (k2 < 128) ? z[(size_t)(row0 + arow) * 128 + k2]
                                   : c[(size_t)(row0 + arow) * 100 + k2 - 128];
                }
            } else {
                const float h = hin[(size_t)(row0 + arow) * HDIM + gk];
                const float s = fmaf(h, scf[gk], shf[gk]);
                v = s > 0.f ? s : 0.f;
            }
            Ash[ahalf + q][arow] = v;
        }
        // ---- B stage (8 cols/thread along one W row: coalesced) ----
        {
            const int gk = kt + bkk;
            if (nfast && gk < K) {
                const float4 w0 = *reinterpret_cast<const float4*>(&W[(size_t)gk * N + n0 + bc]);
                const float4 w1 = *reinterpret_cast<const float4*>(&W[(size_t)gk * N + n0 + bc + 4]);
                *reinterpret_cast<float4*>(&Bsh[bkk][bc])     = w0;
                *reinterpret_cast<float4*>(&Bsh[bkk][bc + 4]) = w1;
            } else {
                #pragma unroll
                for (int q = 0; q < 8; ++q) {
                    const int gn = n0 + bc + q;
                    Bsh[bkk][bc + q] = (gk < K && gn < N) ? W[(size_t)gk * N + gn] : 0.f;
                }
            }
        }
        __syncthreads();
        // ---- compute ----
        #pragma unroll
        for (int kk = 0; kk < KT; ++kk) {
            float a[2][4], b[2][4];
            *reinterpret_cast<float4*>(a[0]) = *reinterpret_cast<const float4*>(&Ash[kk][ty * 4]);
            *reinterpret_cast<float4*>(a[1]) = *reinterpret_cast<const float4*>(&Ash[kk][64 + ty * 4]);
            *reinterpret_cast<float4*>(b[0]) = *reinterpret_cast<const float4*>(&Bsh[kk][tx * 4]);
            *reinterpret_cast<float4*>(b[1]) = *reinterpret_cast<const float4*>(&Bsh[kk][64 + tx * 4]);
            #pragma unroll
            for (int rb = 0; rb < 2; ++rb)
                #pragma unroll
                for (int cb = 0; cb < 2; ++cb)
                    #pragma unroll
                    for (int i = 0; i < 4; ++i)
                        #pragma unroll
                        for (int j = 0; j < 4; ++j)
                            acc[rb][cb][i][j] = fmaf(a[rb][i], b[cb][j], acc[rb][cb][i][j]);
        }
    }

    // ---- epilogue: + bias, store ----
    #pragma unroll
    for (int rb = 0; rb < 2; ++rb)
        #pragma unroll
        for (int i = 0; i < 4; ++i) {
            const size_t row = row0 + rb * 64 + ty * 4 + i;
            #pragma unroll
            for (int cb = 0; cb < 2; ++cb) {
                const int n = n0 + cb * 64 + tx * 4;
                if (nfast) {
                    float4 r;
                    r.x = acc[rb][cb][i][0] + bias[n + 0];
                    r.y = acc[rb][cb][i][1] + bias[n + 1];
                    r.z = acc[rb][cb][i][2] + bias[n + 2];
                    r.w = acc[rb][cb][i][3] + bias[n + 3];
                    *reinterpret_cast<float4*>(&out[row * N + n]) = r;
                } else {
                    #pragma unroll
                    for (int j = 0; j < 4; ++j)
                        if (n + j < N) out[row * N + n + j] = acc[rb][cb][i][j] + bias[n + j];
                }
            }
        }
}

// ---------------------------------------------------------------------------
// Fused column sum + sumsq over f32 h, f64 accumulation. 256 blocks x 64 rows.
// part[b*512 + col] = sum, part[b*512 + 256 + col] = sumsq.
// ---------------------------------------------------------------------------
__global__ __launch_bounds__(256) void colsum2_k(const float* __restrict__ h,
                                                 double* __restrict__ part)
{
    const int col = threadIdx.x;
    const size_t b0 = (size_t)blockIdx.x * 64;
    double s = 0.0, q = 0.0;
    for (int r = 0; r < 64; ++r) {
        const double v = (double)h[(b0 + r) * HDIM + col];
        s += v;
        q = fma(v, v, q);
    }
    part[(size_t)blockIdx.x * 512 + col]       = s;
    part[(size_t)blockIdx.x * 512 + 256 + col] = q;
}

__global__ __launch_bounds__(256) void fin_k(const double* __restrict__ part,
                                             const float* __restrict__ g,
                                             const float* __restrict__ be,
                                             double* __restrict__ sc64,
                                             double* __restrict__ sh64,
                                             float* __restrict__ scf,
                                             float* __restrict__ shf)
{
    const int col = threadIdx.x;
    double s = 0.0, q = 0.0;
    for (int i = 0; i < 256; ++i) {
        s += part[(size_t)i * 512 + col];
        q += part[(size_t)i * 512 + 256 + col];
    }
    const double mu    = s / (double)BATCH;
    const double var   = q / (double)BATCH - mu * mu;  // biased, matches jnp.var
    const double rs    = 1.0 / sqrt(var + 1e-5);
    const double scale = rs * (double)g[col];
    const double shift = (double)be[col] - mu * scale;
    sc64[col] = scale;  sh64[col] = shift;
    scf[col]  = (float)scale;  shf[col] = (float)shift;
}

// ---------------------------------------------------------------------------
// Heads: tanh + hard gumbel one-hot in-place over x (f32, in d_out).
// argmax computed in f64 from f32 logits; groups with top-2 gap < THETA are
// flagged for f64 recompute. One thread per (row, group) -> disjoint writes.
// ---------------------------------------------------------------------------
__global__ __launch_bounds__(256) void heads_k(float* __restrict__ x,
                                               const float* __restrict__ gc,
                                               const float* __restrict__ gd,
                                               int* __restrict__ cnt,
                                               int* __restrict__ list)
{
    const int idx = blockIdx.x * 256 + threadIdx.x;
    const int row = idx / NGRP;
    const int g   = idx % NGRP;

    size_t base;
    const float* gum;
    if (g < 100) {
        base = (size_t)row * DOUTN + (size_t)g * 11 + 1;
        gum  = &gc[((size_t)row * 100 + g) * 10];
    } else {
        base = (size_t)row * DOUTN + 1100 + (size_t)(g - 100) * 10;
        gum  = &gd[((size_t)row * 100 + (g - 100)) * 10];
    }

    int am = 0;
    double best = -1e300, second = -1e300;
    #pragma unroll
    for (int m = 0; m < 10; ++m) {
        const double v = (double)x[base + m] + (double)gum[m];
        if (v > best) { second = best; best = v; am = m; }
        else if (v > second) second = v;
    }
    if (g < 100) {
        const size_t tc = base - 1;
        x[tc] = tanhf(x[tc]);
    }
    #pragma unroll
    for (int m = 0; m < 10; ++m) x[base + m] = (m == am) ? 1.0f : 0.0f;

    if (best - second < THETA) {
        const int p = atomicAdd(cnt, 1);
        if (p < FCAP) list[p] = (row << 8) | g;
    }
}

// ---------------------------------------------------------------------------
// f64 fallback: one block per flagged (row, group). Recomputes that row's
// h1 -> s1 -> h2 -> s2 -> the group's 10 logits entirely in f64 (using the
// f64 BN scale/shift shared with the main path) and rewrites the one-hot.
// W1/W2 (728 KB) stay L2-resident across blocks.
// ---------------------------------------------------------------------------
__global__ __launch_bounds__(256) void fallback_k(
    const float* __restrict__ z,   const float* __restrict__ c,
    const float* __restrict__ W1,  const float* __restrict__ b1,
    const float* __restrict__ W2,  const float* __restrict__ b2,
    const float* __restrict__ Wout,const float* __restrict__ bout,
    const double* __restrict__ sc1,const double* __restrict__ sh1,
    const double* __restrict__ sc2,const double* __restrict__ sh2,
    const float* __restrict__ gc,  const float* __restrict__ gd,
    const int* __restrict__ cnt,   const int* __restrict__ list,
    float* __restrict__ x)
{
    int nf = *cnt;
    if (nf > FCAP) nf = FCAP;
    if ((int)blockIdx.x >= nf) return;
    const int f   = list[blockIdx.x];
    const int row = f >> 8, g = f & 255;
    const int t   = threadIdx.x;

    __shared__ double s1[HDIM], s2[HDIM], lg[16];

    // h1[t]
    double a = (double)b1[t];
    for (int k = 0; k < DIN; ++k) {
        const double iv = (k < 128) ? (double)z[(size_t)row * 128 + k]
                                    : (double)c[(size_t)row * 100 + k - 128];
        a = fma(iv, (double)W1[(size_t)k * HDIM + t], a);
    }
    const double v1 = fma(a, sc1[t], sh1[t]);
    s1[t] = v1 > 0.0 ? v1 : 0.0;
    __syncthreads();

    // h2[t]
    double a2 = (double)b2[t];
    for (int k = 0; k < HDIM; ++k)
        a2 = fma(s1[k], (double)W2[(size_t)k * HDIM + t], a2);
    for (int k = 0; k < DIN; ++k) {
        const double iv = (k < 128) ? (double)z[(size_t)row * 128 + k]
                                    : (double)c[(size_t)row * 100 + k - 128];
        a2 = fma(iv, (double)W2[(size_t)(HDIM + k) * HDIM + t], a2);
    }
    const double v2 = fma(a2, sc2[t], sh2[t]);
    s2[t] = v2 > 0.0 ? v2 : 0.0;
    __syncthreads();

    // group logits + gumbel
    if (t < 10) {
        const int col = (g < 100) ? g * 11 + 1 + t : 1100 + (g - 100) * 10 + t;
        double d = (double)bout[col];
        for (int k = 0; k < HDIM; ++k)
            d = fma(s2[k], (double)Wout[(size_t)k * DOUTN + col], d);
        const double gv = (g < 100) ? (double)gc[((size_t)row * 100 + g) * 10 + t]
                                    : (double)gd[((size_t)row * 100 + (g - 100)) * 10 + t];
        lg[t] = d + gv;
    }
    __syncthreads();

    if (t == 0) {
        int am = 0;
        double best = lg[0];
        #pragma unroll
        for (int m = 1; m < 10; ++m)
            if (lg[m] > best) { best = lg[m]; am = m; }
        const size_t base = (g < 100) ? (size_t)row * DOUTN + (size_t)g * 11 + 1
                                      : (size_t)row * DOUTN + 1100 + (size_t)(g - 100) * 10;
        #pragma unroll
        for (int m = 0; m < 10; ++m) x[base + m] = (m == am) ? 1.0f : 0.0f;
    }
}

__global__ void zero_k(int* cnt) { if (threadIdx.x == 0) *cnt = 0; }

// ---------------------------------------------------------------------------
extern "C" void kernel_launch(void* const* d_in, const int* in_sizes, int n_in,
                              void* d_out, int out_size, void* d_ws, size_t ws_size,
                              hipStream_t stream)
{
    (void)in_sizes; (void)n_in; (void)out_size; (void)ws_size;

    const float* z    = (const float*)d_in[0];
    const float* c    = (const float*)d_in[1];
    const float* W1   = (const float*)d_in[2];
    const float* b1   = (const float*)d_in[3];
    const float* g1   = (const float*)d_in[4];
    const float* be1  = (const float*)d_in[5];
    const float* W2   = (const float*)d_in[6];
    const float* b2   = (const float*)d_in[7];
    const float* g2   = (const float*)d_in[8];
    const float* be2  = (const float*)d_in[9];
    const float* Wout = (const float*)d_in[10];
    const float* bout = (const float*)d_in[11];
    const float* gc   = (const float*)d_in[12];
    const float* gd   = (const float*)d_in[13];
    float* out = (float*)d_out;

    // workspace: f64 first (alignment), then f32, then ints
    double* part = (double*)d_ws;              // 256*512
    double* sc1  = part + 256 * 512;
    double* sh1  = sc1 + HDIM;
    double* sc2  = sh1 + HDIM;
    double* sh2  = sc2 + HDIM;
    float*  scf1 = (float*)(sh2 + HDIM);
    float*  shf1 = scf1 + HDIM;
    float*  scf2 = shf1 + HDIM;
    float*  shf2 = scf2 + HDIM;
    float*  h1   = shf2 + HDIM;                // BATCH*HDIM f32
    float*  h2   = h1 + (size_t)BATCH * HDIM;
    int*    cnt  = (int*)(h2 + (size_t)BATCH * HDIM);
    int*    list = cnt + 1;

    const dim3 blk(256);
    const dim3 gridH(2, BATCH / 128);    // (2, 128)
    const dim3 gridO(17, BATCH / 128);   // ceil(2100/128)=17

    zero_k<<<dim3(1), dim3(64), 0, stream>>>(cnt);

    gemm_f32<0><<<gridH, blk, 0, stream>>>(z, c, nullptr, nullptr, nullptr, W1, b1, h1);
    colsum2_k<<<dim3(256), blk, 0, stream>>>(h1, part);
    fin_k<<<dim3(1), blk, 0, stream>>>(part, g1, be1, sc1, sh1, scf1, shf1);

    gemm_f32<1><<<gridH, blk, 0, stream>>>(z, c, h1, scf1, shf1, W2, b2, h2);
    colsum2_k<<<dim3(256), blk, 0, stream>>>(h2, part);
    fin_k<<<dim3(1), blk, 0, stream>>>(part, g2, be2, sc2, sh2, scf2, shf2);

    gemm_f32<2><<<gridO, blk, 0, stream>>>(z, c, h2, scf2, shf2, Wout, bout, out);

    heads_k<<<dim3(BATCH * NGRP / 256), blk, 0, stream>>>(out, gc, gd, cnt, list);
    fallback_k<<<dim3(FCAP), blk, 0, stream>>>(z, c, W1, b1, W2, b2, Wout, bout,
                                               sc1, sh1, sc2, sh2, gc, gd, cnt, list, out);
}